// Round 1
// 465.925 us; speedup vs baseline: 1.0284x; 1.0284x over previous
//
#include <hip/hip_runtime.h>
#include <hip/hip_bf16.h>

typedef __attribute__((ext_vector_type(8))) short bf16x8;   // 8 bf16 in 4 VGPRs
typedef __attribute__((ext_vector_type(4))) float f32x4;    // MFMA accumulator

#define S77  77
#define NQ   80
#define CS   136   // stage row stride (shorts): 128 cols + 8 pad; 272B/row = 0 mod 16, 68 dw = 4 mod 32 (conflict-clean)
#define KS2  104   // KfT/VsT row stride (shorts): 96 s + 8 pad; 208B = 0 mod 16, 52 dw = 20 mod 32 (conflict-clean)

#define MFMA(a,b,c) __builtin_amdgcn_mfma_f32_16x16x32_bf16((a),(b),(c),0,0,0)

__device__ __forceinline__ unsigned int cvt_pk(float a, float b) {
    union { __hip_bfloat162 h; unsigned int u; } c;
    c.h = __float22bfloat162_rn(make_float2(a, b));   // v_cvt_pk_bf16_f32
    return c.u;
}
__device__ __forceinline__ unsigned short f2bf(float f) {
    union { __hip_bfloat16 h; unsigned short u; } c;
    c.h = __float2bfloat16(f);
    return c.u;
}

// ws layout (bf16 elems): WqT [128][256] @0, WkT [128][256] @32768, WvT [128][128] @65536
__global__ void transpose_weights(const float* __restrict__ Wq,
                                  const float* __restrict__ Wk,
                                  const float* __restrict__ Wv,
                                  unsigned short* __restrict__ ws) {
    int t = blockIdx.x * 256 + threadIdx.x;
    if (t < 32768) {                // Wq (256x128) -> WqT
        int k = t >> 7, c = t & 127;
        ws[c * 256 + k] = f2bf(Wq[t]);
    } else if (t < 65536) {         // Wk
        int u = t - 32768; int k = u >> 7, c = u & 127;
        ws[32768 + c * 256 + k] = f2bf(Wk[u]);
    } else if (t < 81920) {         // Wv (128x128) -> WvT
        int u = t - 65536; int k = u >> 7, c = u & 127;
        ws[65536 + c * 128 + k] = f2bf(Wv[u]);
    }
}

// 512 threads = 8 waves = 2 row-groups (rg) x 4 col-groups (cg).
// Wave (rg,cg): rows rg*48..(+48), cols cg*32..(+32) = heads 2cg, 2cg+1.
// LDS 54,272 B -> 2 blocks/CU (3 possible if VGPR <= 85).
__global__ __launch_bounds__(512, 4)
void attn_kernel(const float* __restrict__ query,   // (4,80,24,24,256) f32
                 const float* __restrict__ x,       // (2304,77,128) f32
                 const float* __restrict__ guid,    // (2304,77,128) f32
                 const unsigned short* __restrict__ wT,
                 const float* __restrict__ bq,
                 const float* __restrict__ bk,
                 const float* __restrict__ bv,
                 float* __restrict__ out)            // (2304,128) f32
{
    const int n    = blockIdx.x;
    const int tid  = threadIdx.x;
    const int wid  = tid >> 6;      // wave 0..7
    const int lane = tid & 63;
    const int quad = lane >> 4;     // 0..3
    const int mr   = lane & 15;
    const int rg   = wid >> 2;      // row group 0/1
    const int cg   = wid & 3;       // col group 0..3
    const int b    = n / 576;
    const int hw   = n % 576;
    const int r0   = rg * 48;       // wave's row base

    // Union: stage dbuf (pass1 XG chunks / pass2 Q chunks), then KfT/VsT transpose,
    // finally qbar partials. All transitions guarded by barriers.
    __shared__ union {
        unsigned short stage[2][96 * CS];    // 52,224 B
        unsigned short tr[2][128 * KS2];     // 53,248 B : tr[0]=KfT, tr[1]=VsT (channel-major, s cols)
        float qbar[256];                     // Qbar partials [rg][128]
    } U;
    __shared__ float KsumP[256];             // Ksum partials [rg][128]

    const unsigned short* WqT = wT;
    const unsigned short* WkT = wT + 32768;
    const unsigned short* WvT = wT + 65536;
    const f32x4 cZ = {0.f, 0.f, 0.f, 0.f};

    const float* xg = x    + (size_t)n * S77 * 128;
    const float* gg = guid + (size_t)n * S77 * 128;

    const int srow = tid >> 5;   // staging row within 16-row strip
    const int seg  = tid & 31;   // float4 segment within 128 cols

    float4 sb[5];

    // =================== PASS 1: K = [x,g]@Wk, V = x@Wv ===================
    f32x4 Kacc[3][2], Vacc[3][2];
    #pragma unroll
    for (int i = 0; i < 3; ++i) {
        Kacc[i][0] = cZ; Kacc[i][1] = cZ;
        Vacc[i][0] = cZ; Vacc[i][1] = cZ;
    }

    // stage chunk 0 (x, cols 0..127)
    #pragma unroll
    for (int it = 0; it < 5; ++it) {
        const int s = srow + it * 16;
        if (s < S77) sb[it] = *(const float4*)(xg + (size_t)s * 128 + seg * 4);
    }
    #pragma unroll
    for (int it = 0; it < 5; ++it) {
        const int s = srow + it * 16;
        if (s < S77) {
            uint2 p; p.x = cvt_pk(sb[it].x, sb[it].y); p.y = cvt_pk(sb[it].z, sb[it].w);
            *(uint2*)&U.stage[0][s * CS + seg * 4] = p;
        }
    }
    __syncthreads();

    #pragma unroll
    for (int c = 0; c < 2; ++c) {
        if (c == 0) {   // prefetch chunk 1 (guid) early: latency hides under compute
            #pragma unroll
            for (int it = 0; it < 5; ++it) {
                const int s = srow + it * 16;
                if (s < S77) sb[it] = *(const float4*)(gg + (size_t)s * 128 + seg * 4);
            }
        }
        const unsigned short* sbase = U.stage[c];
        #pragma unroll
        for (int kk = 0; kk < 4; ++kk) {
            const int kloc  = kk * 32 + quad * 8;
            const int kglob = c * 128 + kk * 32;
            bf16x8 a0 = *(const bf16x8*)&sbase[(r0      + mr) * CS + kloc];
            bf16x8 a1 = *(const bf16x8*)&sbase[(r0 + 16 + mr) * CS + kloc];
            bf16x8 a2;
            if (rg == 0) a2 = *(const bf16x8*)&sbase[(32 + mr) * CS + kloc];  // rg1's 3rd tile is all-pad: skip
            #pragma unroll
            for (int t = 0; t < 2; ++t) {
                const int cc = cg * 32 + t * 16 + mr;
                bf16x8 bkf = *(const bf16x8*)(WkT + cc * 256 + kglob + quad * 8);
                Kacc[0][t] = MFMA(a0, bkf, Kacc[0][t]);
                Kacc[1][t] = MFMA(a1, bkf, Kacc[1][t]);
                if (rg == 0) Kacc[2][t] = MFMA(a2, bkf, Kacc[2][t]);
                if (c == 0) {   // V GEMM shares the same A-fragments (x half) -> free A reads
                    bf16x8 bvf = *(const bf16x8*)(WvT + cc * 128 + kglob + quad * 8);
                    Vacc[0][t] = MFMA(a0, bvf, Vacc[0][t]);
                    Vacc[1][t] = MFMA(a1, bvf, Vacc[1][t]);
                    if (rg == 0) Vacc[2][t] = MFMA(a2, bvf, Vacc[2][t]);
                }
            }
        }
        if (c == 0) {   // write prefetched guid chunk to buffer 1 (other buffer: no race)
            #pragma unroll
            for (int it = 0; it < 5; ++it) {
                const int s = srow + it * 16;
                if (s < S77) {
                    uint2 p; p.x = cvt_pk(sb[it].x, sb[it].y); p.y = cvt_pk(sb[it].z, sb[it].w);
                    *(uint2*)&U.stage[1][s * CS + seg * 4] = p;
                }
            }
        }
        __syncthreads();
    }

    // --------- pass-1 epilogue: elu+1, KfT/VsT (transposed, zero-padded), Ksum partials ---------
    #pragma unroll
    for (int t = 0; t < 2; ++t) {
        const int cc = cg * 32 + t * 16 + mr;
        const float biask = bk[cc];
        const float biasv = bv[cc];
        float ksp = 0.f;
        #pragma unroll
        for (int mt = 0; mt < 3; ++mt) {
            const int s0 = r0 + mt * 16 + quad * 4;
            float kv4[4], vv4[4];
            #pragma unroll
            for (int r = 0; r < 4; ++r) {
                const int s = s0 + r;
                float tk = 0.f, tv = 0.f;
                if (s < S77) {
                    tk = Kacc[mt][t][r] + biask;
                    tk = (tk > 0.f) ? (tk + 1.f) : __expf(tk);   // elu+1
                    tv = Vacc[mt][t][r] + biasv;
                }
                kv4[r] = tk; vv4[r] = tv; ksp += tk;
            }
            uint2 pk_; pk_.x = cvt_pk(kv4[0], kv4[1]); pk_.y = cvt_pk(kv4[2], kv4[3]);
            *(uint2*)&U.tr[0][cc * KS2 + s0] = pk_;
            uint2 pv_; pv_.x = cvt_pk(vv4[0], vv4[1]); pv_.y = cvt_pk(vv4[2], vv4[3]);
            *(uint2*)&U.tr[1][cc * KS2 + s0] = pv_;
        }
        ksp += __shfl_xor(ksp, 16);
        ksp += __shfl_xor(ksp, 32);
        if (quad == 0) KsumP[rg * 128 + cc] = ksp;
    }

    // prefetch Q chunk 0 now: latency hides under phase C
    #pragma unroll
    for (int it = 0; it < 5; ++it) {
        const int l = srow + it * 16;   // 0..79 exactly
        sb[it] = *(const float4*)(query + ((size_t)(b * 80 + l) * 576 + hw) * 256 + seg * 4);
    }
    __syncthreads();   // KfT/VsT/KsumP visible

    // --------- phase C: KV_h = Kf_h^T @ V_h (K=96, zero-padded); head h = wid ---------
    f32x4 KVacc = cZ;   // KV[h][quad*4+r][mr], lives in 4 VGPRs through pass 2
    #pragma unroll
    for (int ks3 = 0; ks3 < 3; ++ks3) {
        const int sc = ks3 * 32 + quad * 8;
        bf16x8 a  = *(const bf16x8*)&U.tr[0][(wid * 16 + mr) * KS2 + sc];
        bf16x8 bb = *(const bf16x8*)&U.tr[1][(wid * 16 + mr) * KS2 + sc];
        KVacc = MFMA(a, bb, KVacc);
    }
    __syncthreads();   // tr reads done; union region free for pass 2

    // =================== PASS 2: Q = query@Wq ===================
    f32x4 Qacc[3][2];
    #pragma unroll
    for (int i = 0; i < 3; ++i) { Qacc[i][0] = cZ; Qacc[i][1] = cZ; }

    #pragma unroll
    for (int it = 0; it < 5; ++it) {
        const int l = srow + it * 16;
        uint2 p; p.x = cvt_pk(sb[it].x, sb[it].y); p.y = cvt_pk(sb[it].z, sb[it].w);
        *(uint2*)&U.stage[0][l * CS + seg * 4] = p;
    }
    __syncthreads();

    #pragma unroll
    for (int c = 0; c < 2; ++c) {
        if (c == 0) {   // prefetch Q chunk 1 (cols 128..255)
            #pragma unroll
            for (int it = 0; it < 5; ++it) {
                const int l = srow + it * 16;
                sb[it] = *(const float4*)(query + ((size_t)(b * 80 + l) * 576 + hw) * 256 + 128 + seg * 4);
            }
        }
        const unsigned short* sbase = U.stage[c];
        #pragma unroll
        for (int kk = 0; kk < 4; ++kk) {
            const int kloc  = kk * 32 + quad * 8;
            const int kglob = c * 128 + kk * 32;
            bf16x8 a0 = *(const bf16x8*)&sbase[(r0      + mr) * CS + kloc];
            bf16x8 a1 = *(const bf16x8*)&sbase[(r0 + 16 + mr) * CS + kloc];
            bf16x8 a2;
            if (rg == 0) a2 = *(const bf16x8*)&sbase[(32 + mr) * CS + kloc];
            #pragma unroll
            for (int t = 0; t < 2; ++t) {
                const int cc = cg * 32 + t * 16 + mr;
                bf16x8 bqf = *(const bf16x8*)(WqT + cc * 256 + kglob + quad * 8);
                Qacc[0][t] = MFMA(a0, bqf, Qacc[0][t]);
                Qacc[1][t] = MFMA(a1, bqf, Qacc[1][t]);
                if (rg == 0) Qacc[2][t] = MFMA(a2, bqf, Qacc[2][t]);
            }
        }
        if (c == 0) {
            #pragma unroll
            for (int it = 0; it < 5; ++it) {
                const int l = srow + it * 16;
                uint2 p; p.x = cvt_pk(sb[it].x, sb[it].y); p.y = cvt_pk(sb[it].z, sb[it].w);
                *(uint2*)&U.stage[1][l * CS + seg * 4] = p;
            }
        }
        __syncthreads();
    }

    // --------- pass-2 epilogue: z + Qbar entirely in-register (head-aligned cols) ---------
    #pragma unroll
    for (int t = 0; t < 2; ++t) {
        const int cc = cg * 32 + t * 16 + mr;
        const float biasq = bq[cc];
        const float ksc = KsumP[cc] + KsumP[128 + cc];   // full Ksum for this channel
        float qb = 0.f;
        #pragma unroll
        for (int mt = 0; mt < 3; ++mt) {
            if (!(rg == 1 && mt == 2)) {   // rg1 tile 2 = rows 80..95: all pad
                #pragma unroll
                for (int r = 0; r < 4; ++r) {
                    float qv = Qacc[mt][t][r] + biasq;
                    qv = (qv > 0.f) ? (qv + 1.f) : __expf(qv);   // elu+1, all rows here are real (l<80)
                    float den = qv * ksc;
                    den += __shfl_xor(den, 1);   // reduce over the 16 mr lanes (head dot product)
                    den += __shfl_xor(den, 2);
                    den += __shfl_xor(den, 4);
                    den += __shfl_xor(den, 8);
                    qb += qv * (1.f / (den + 1e-6f));            // z_l * Q[l,cc]
                }
            }
        }
        qb += __shfl_xor(qb, 16);   // sum over this wave's rows (quads)
        qb += __shfl_xor(qb, 32);
        if (quad == 0) U.qbar[rg * 128 + cc] = qb;   // aliases dead stage[0]
    }
    __syncthreads();

    // --------- final: out[h*16+e] = (Qbar_h . KV_h[:,e]) / 80 ; head h = wid ---------
    {
        float o = 0.f;
        #pragma unroll
        for (int r = 0; r < 4; ++r) {
            const int d = wid * 16 + quad * 4 + r;
            const float qbar = U.qbar[d] + U.qbar[128 + d];   // broadcast read (same addr across mr)
            o += qbar * KVacc[r];
        }
        o += __shfl_xor(o, 16);
        o += __shfl_xor(o, 32);
        if (quad == 0) out[(size_t)n * 128 + wid * 16 + mr] = o * (1.f / 80.f);
    }
}

extern "C" void kernel_launch(void* const* d_in, const int* in_sizes, int n_in,
                              void* d_out, int out_size, void* d_ws, size_t ws_size,
                              hipStream_t stream) {
    const float* query = (const float*)d_in[0];
    const float* x     = (const float*)d_in[1];
    const float* g     = (const float*)d_in[2];
    const float* Wq    = (const float*)d_in[3];
    const float* bq    = (const float*)d_in[4];
    const float* Wk    = (const float*)d_in[5];
    const float* bk    = (const float*)d_in[6];
    const float* Wv    = (const float*)d_in[7];
    const float* bv    = (const float*)d_in[8];
    float* out = (float*)d_out;
    unsigned short* ws = (unsigned short*)d_ws;   // 163,840 B used

    hipLaunchKernelGGL(transpose_weights, dim3(320), dim3(256), 0, stream, Wq, Wk, Wv, ws);
    hipLaunchKernelGGL(attn_kernel, dim3(2304), dim3(512), 0, stream,
                       query, x, g, ws, bq, bk, bv, out);
}

// Round 2
// 439.480 us; speedup vs baseline: 1.0903x; 1.0602x over previous
//
#include <hip/hip_runtime.h>
#include <hip/hip_bf16.h>

typedef __attribute__((ext_vector_type(8))) short bf16x8;   // 8 bf16 in 4 VGPRs
typedef __attribute__((ext_vector_type(4))) float f32x4;    // MFMA accumulator

#define S77 77
#define CS  136   // stage row stride (shorts): 272B/row, 68 dw = 4 mod 32 -> 2-way (free) on b128 reads

#define MFMA(a,b,c) __builtin_amdgcn_mfma_f32_16x16x32_bf16((a),(b),(c),0,0,0)

__device__ __forceinline__ unsigned int cvt_pk(float a, float b) {
    union { __hip_bfloat162 h; unsigned int u; } c;
    c.h = __float22bfloat162_rn(make_float2(a, b));   // v_cvt_pk_bf16_f32
    return c.u;
}
__device__ __forceinline__ unsigned short f2bf(float f) {
    union { __hip_bfloat16 h; unsigned short u; } c;
    c.h = __float2bfloat16(f);
    return c.u;
}

// ws layout (bf16 elems): WqT [128][256] @0, WkT [128][256] @32768, WvT [128][128] @65536
__global__ void transpose_weights(const float* __restrict__ Wq,
                                  const float* __restrict__ Wk,
                                  const float* __restrict__ Wv,
                                  unsigned short* __restrict__ ws) {
    int t = blockIdx.x * 256 + threadIdx.x;
    if (t < 32768) {                // Wq (256x128) -> WqT
        int k = t >> 7, c = t & 127;
        ws[c * 256 + k] = f2bf(Wq[t]);
    } else if (t < 65536) {         // Wk
        int u = t - 32768; int k = u >> 7, c = u & 127;
        ws[32768 + c * 256 + k] = f2bf(Wk[u]);
    } else if (t < 81920) {         // Wv (128x128) -> WvT
        int u = t - 65536; int k = u >> 7, c = u & 127;
        ws[65536 + c * 128 + k] = f2bf(Wv[u]);
    }
}

// In-register transpose: build a 16x16x32 A/B-fragment whose k-axis runs over the
// 32 s-rows held in two C-layout tiles t0 (s_local 0..15) and t1 (s_local 16..31).
// C-layout: lane (q,d) reg r holds T[s_local = q*4+r][d].
// A-layout target: lane (q',d) slot j holds T[s_local = q'*8+j][d]
//   -> tile = q'>>1, src quad = (q'&1)*2 + (j>>2), reg = j&3.
// Pack (t0[r], t1[r]) into one u32 via cvt_pk, one bpermute moves both tiles,
// consumer selects half by (quad&2).
__device__ __forceinline__ bf16x8 xpose_frag(const float t0[4], const float t1[4],
                                             int quad, int mr) {
    unsigned int pk[4];
    #pragma unroll
    for (int r = 0; r < 4; ++r) pk[r] = cvt_pk(t0[r], t1[r]);   // lo=t0, hi=t1
    const int sb0 = ((quad & 1) * 2) * 16 + mr;   // src lane for j<4; +16 for j>=4
    unsigned int g0[4], g1[4];
    #pragma unroll
    for (int r = 0; r < 4; ++r) {
        g0[r] = __shfl(pk[r], sb0);
        g1[r] = __shfl(pk[r], sb0 + 16);
    }
    const unsigned int sh = (quad & 2) ? 16u : 0u;   // quads 2,3 take tile1 (hi half)
    union { unsigned int u[4]; bf16x8 v; } o;
    o.u[0] = ((g0[0] >> sh) & 0xffffu) | (((g0[1] >> sh) & 0xffffu) << 16);
    o.u[1] = ((g0[2] >> sh) & 0xffffu) | (((g0[3] >> sh) & 0xffffu) << 16);
    o.u[2] = ((g1[0] >> sh) & 0xffffu) | (((g1[1] >> sh) & 0xffffu) << 16);
    o.u[3] = ((g1[2] >> sh) & 0xffffu) | (((g1[3] >> sh) & 0xffffu) << 16);
    return o.v;
}

// 512 threads = 8 waves; wave h owns head h end-to-end. Only cross-wave coupling:
// the cooperatively staged A-operands (x/guid, then query). 4 barriers total.
// LDS = 43,520 B (stage dbuf only).
__global__ __launch_bounds__(512, 4)
void attn_kernel(const float* __restrict__ query,   // (4,80,24,24,256) f32
                 const float* __restrict__ x,       // (2304,77,128) f32
                 const float* __restrict__ guid,    // (2304,77,128) f32
                 const unsigned short* __restrict__ wT,
                 const float* __restrict__ bq,
                 const float* __restrict__ bk,
                 const float* __restrict__ bv,
                 float* __restrict__ out)            // (2304,128) f32
{
    const int n    = blockIdx.x;
    const int tid  = threadIdx.x;
    const int h    = tid >> 6;      // wave = head 0..7
    const int lane = tid & 63;
    const int quad = lane >> 4;
    const int mr   = lane & 15;
    const int b    = n / 576;
    const int hw   = n % 576;

    __shared__ unsigned short stage[2][80 * CS];    // 2 x 21,760 B

    const unsigned short* WqT = wT;
    const unsigned short* WkT = wT + 32768;
    const unsigned short* WvT = wT + 65536;
    const f32x4 cZ = {0.f, 0.f, 0.f, 0.f};

    const float* xg = x    + (size_t)n * S77 * 128;
    const float* gg = guid + (size_t)n * S77 * 128;
    const int srow = tid >> 5;   // staging row within 16-row strip
    const int seg  = tid & 31;   // float4 segment within 128 cols

    const int cc = h * 16 + mr;                       // this lane's output channel
    const float bk_c = bk[cc], bv_c = bv[cc], bq_c = bq[cc];

    // Preload chunk-0 weights (no deps; L2 latency hides under staging)
    bf16x8 wk0[4], wv0[4];
    #pragma unroll
    for (int kk = 0; kk < 4; ++kk) {
        wk0[kk] = *(const bf16x8*)(WkT + cc * 256 + kk * 32 + quad * 8);
        wv0[kk] = *(const bf16x8*)(WvT + cc * 128 + kk * 32 + quad * 8);
    }

    float4 sb[5];
    // stage x -> buf0
    #pragma unroll
    for (int it = 0; it < 5; ++it) {
        const int s = srow + it * 16;
        if (s < S77) sb[it] = *(const float4*)(xg + (size_t)s * 128 + seg * 4);
    }
    #pragma unroll
    for (int it = 0; it < 5; ++it) {
        const int s = srow + it * 16;
        if (s < S77) {
            uint2 p; p.x = cvt_pk(sb[it].x, sb[it].y); p.y = cvt_pk(sb[it].z, sb[it].w);
            *(uint2*)&stage[0][s * CS + seg * 4] = p;
        }
    }
    // issue guid loads now; land during chunk-0 compute
    #pragma unroll
    for (int it = 0; it < 5; ++it) {
        const int s = srow + it * 16;
        if (s < S77) sb[it] = *(const float4*)(gg + (size_t)s * 128 + seg * 4);
    }
    __syncthreads();   // B1: buf0 (x) ready

    // ---- chunk 0: K += x@Wk[0:128], V = x@Wv (A-frags shared) ----
    f32x4 Kacc[5], Vacc[5];
    #pragma unroll
    for (int m = 0; m < 5; ++m) { Kacc[m] = cZ; Vacc[m] = cZ; }
    #pragma unroll
    for (int kk = 0; kk < 4; ++kk)
        #pragma unroll
        for (int m = 0; m < 5; ++m) {
            bf16x8 a = *(const bf16x8*)&stage[0][(m * 16 + mr) * CS + kk * 32 + quad * 8];
            Kacc[m] = MFMA(a, wk0[kk], Kacc[m]);
            Vacc[m] = MFMA(a, wv0[kk], Vacc[m]);
        }

    bf16x8 wk1[4];
    #pragma unroll
    for (int kk = 0; kk < 4; ++kk)
        wk1[kk] = *(const bf16x8*)(WkT + cc * 256 + 128 + kk * 32 + quad * 8);

    // write guid -> buf1; issue query chunk-0 loads
    #pragma unroll
    for (int it = 0; it < 5; ++it) {
        const int s = srow + it * 16;
        if (s < S77) {
            uint2 p; p.x = cvt_pk(sb[it].x, sb[it].y); p.y = cvt_pk(sb[it].z, sb[it].w);
            *(uint2*)&stage[1][s * CS + seg * 4] = p;
        }
    }
    #pragma unroll
    for (int it = 0; it < 5; ++it) {
        const int l = srow + it * 16;   // 0..79
        sb[it] = *(const float4*)(query + ((size_t)(b * 80 + l) * 576 + hw) * 256 + seg * 4);
    }
    __syncthreads();   // B2: buf1 (guid) ready; buf0 readers done

    // ---- chunk 1: K += guid@Wk[128:256] ----
    #pragma unroll
    for (int kk = 0; kk < 4; ++kk)
        #pragma unroll
        for (int m = 0; m < 5; ++m) {
            bf16x8 a = *(const bf16x8*)&stage[1][(m * 16 + mr) * CS + kk * 32 + quad * 8];
            Kacc[m] = MFMA(a, wk1[kk], Kacc[m]);
        }

    // ---- epilogue 1 (per-wave, no barrier): elu+1, mask, Ksum, in-register KV ----
    float kf[5][4], vs[5][4];
    float ksum = 0.f;
    #pragma unroll
    for (int m = 0; m < 5; ++m)
        #pragma unroll
        for (int r = 0; r < 4; ++r) {
            const int s = m * 16 + quad * 4 + r;
            float tk = 0.f, tv = 0.f;
            if (s < S77) {
                tk = Kacc[m][r] + bk_c;
                tk = (tk > 0.f) ? (tk + 1.f) : __expf(tk);   // elu+1
                tv = Vacc[m][r] + bv_c;
            }
            kf[m][r] = tk; vs[m][r] = tv; ksum += tk;
        }
    ksum += __shfl_xor(ksum, 16);   // sum over quads -> Ksum[d=mr] at every lane
    ksum += __shfl_xor(ksum, 32);

    const float z4[4] = {0.f, 0.f, 0.f, 0.f};
    f32x4 KVacc = cZ;   // KV[d = quad*4+r][e = mr], 4 VGPRs, live to the end
    {
        bf16x8 af, bf;
        af = xpose_frag(kf[0], kf[1], quad, mr);
        bf = xpose_frag(vs[0], vs[1], quad, mr);
        KVacc = MFMA(af, bf, KVacc);
        af = xpose_frag(kf[2], kf[3], quad, mr);
        bf = xpose_frag(vs[2], vs[3], quad, mr);
        KVacc = MFMA(af, bf, KVacc);
        af = xpose_frag(kf[4], z4, quad, mr);    // s 80..95 = zero tile
        bf = xpose_frag(vs[4], z4, quad, mr);
        KVacc = MFMA(af, bf, KVacc);
    }

    // write query c0 -> buf0 (safe: buf0 readers done at B2); issue query c1 loads
    #pragma unroll
    for (int it = 0; it < 5; ++it) {
        const int l = srow + it * 16;
        uint2 p; p.x = cvt_pk(sb[it].x, sb[it].y); p.y = cvt_pk(sb[it].z, sb[it].w);
        *(uint2*)&stage[0][l * CS + seg * 4] = p;
    }
    #pragma unroll
    for (int it = 0; it < 5; ++it) {
        const int l = srow + it * 16;
        sb[it] = *(const float4*)(query + ((size_t)(b * 80 + l) * 576 + hw) * 256 + 128 + seg * 4);
    }
    bf16x8 wq0[4];
    #pragma unroll
    for (int kk = 0; kk < 4; ++kk)
        wq0[kk] = *(const bf16x8*)(WqT + cc * 256 + kk * 32 + quad * 8);
    __syncthreads();   // B3: buf0 (query c0) ready; buf1 readers done

    // ---- Q chunk 0 ----
    f32x4 Qacc[5];
    #pragma unroll
    for (int m = 0; m < 5; ++m) Qacc[m] = cZ;
    #pragma unroll
    for (int kk = 0; kk < 4; ++kk)
        #pragma unroll
        for (int m = 0; m < 5; ++m) {
            bf16x8 a = *(const bf16x8*)&stage[0][(m * 16 + mr) * CS + kk * 32 + quad * 8];
            Qacc[m] = MFMA(a, wq0[kk], Qacc[m]);
        }
    bf16x8 wq1[4];
    #pragma unroll
    for (int kk = 0; kk < 4; ++kk)
        wq1[kk] = *(const bf16x8*)(WqT + cc * 256 + 128 + kk * 32 + quad * 8);
    #pragma unroll
    for (int it = 0; it < 5; ++it) {
        const int l = srow + it * 16;
        uint2 p; p.x = cvt_pk(sb[it].x, sb[it].y); p.y = cvt_pk(sb[it].z, sb[it].w);
        *(uint2*)&stage[1][l * CS + seg * 4] = p;
    }
    __syncthreads();   // B4: buf1 (query c1) ready

    // ---- Q chunk 1 ----
    #pragma unroll
    for (int kk = 0; kk < 4; ++kk)
        #pragma unroll
        for (int m = 0; m < 5; ++m) {
            bf16x8 a = *(const bf16x8*)&stage[1][(m * 16 + mr) * CS + kk * 32 + quad * 8];
            Qacc[m] = MFMA(a, wq1[kk], Qacc[m]);
        }

    // ---- epilogue 2 (per-wave): z, qbar, out — all in-register ----
    float qbar = 0.f;
    #pragma unroll
    for (int m = 0; m < 5; ++m)
        #pragma unroll
        for (int r = 0; r < 4; ++r) {
            float qv = Qacc[m][r] + bq_c;
            qv = (qv > 0.f) ? (qv + 1.f) : __expf(qv);   // elu+1 (l always < 80)
            float den = qv * ksum;
            den += __shfl_xor(den, 1);   // dot over d = mr lanes (same l across quad)
            den += __shfl_xor(den, 2);
            den += __shfl_xor(den, 4);
            den += __shfl_xor(den, 8);
            qbar += qv * (1.f / (den + 1e-6f));          // z_l * Q[l,d]
        }
    qbar += __shfl_xor(qbar, 16);   // sum over quads -> Qbar[d=mr] at every lane
    qbar += __shfl_xor(qbar, 32);

    float o = 0.f;
    #pragma unroll
    for (int r = 0; r < 4; ++r) {
        const float qb_r = __shfl(qbar, quad * 4 + r);   // Qbar[quad*4+r]
        o += qb_r * KVacc[r];                            // KV[quad*4+r][mr]
    }
    o += __shfl_xor(o, 16);   // sum over quads -> full d contraction
    o += __shfl_xor(o, 32);
    if (quad == 0) out[(size_t)n * 128 + cc] = o * (1.f / 80.f);
}

extern "C" void kernel_launch(void* const* d_in, const int* in_sizes, int n_in,
                              void* d_out, int out_size, void* d_ws, size_t ws_size,
                              hipStream_t stream) {
    const float* query = (const float*)d_in[0];
    const float* x     = (const float*)d_in[1];
    const float* g     = (const float*)d_in[2];
    const float* Wq    = (const float*)d_in[3];
    const float* bq    = (const float*)d_in[4];
    const float* Wk    = (const float*)d_in[5];
    const float* bk    = (const float*)d_in[6];
    const float* Wv    = (const float*)d_in[7];
    const float* bv    = (const float*)d_in[8];
    float* out = (float*)d_out;
    unsigned short* ws = (unsigned short*)d_ws;   // 163,840 B used

    hipLaunchKernelGGL(transpose_weights, dim3(320), dim3(256), 0, stream, Wq, Wk, Wv, ws);
    hipLaunchKernelGGL(attn_kernel, dim3(2304), dim3(512), 0, stream,
                       query, x, g, ws, bq, bk, bv, out);
}

// Round 5
// 437.812 us; speedup vs baseline: 1.0944x; 1.0038x over previous
//
#include <hip/hip_runtime.h>
#include <hip/hip_bf16.h>

typedef __attribute__((ext_vector_type(8))) short bf16x8;        // 8 bf16 in 4 VGPRs
typedef __attribute__((ext_vector_type(4))) float f32x4;         // MFMA accumulator
typedef __attribute__((ext_vector_type(4))) unsigned int u32x4;  // packed bf16 pairs

#define S77 77
#define CS  136   // stage row stride (shorts): 272B/row, conflict profile measured OK

#define MFMA(a,b,c) __builtin_amdgcn_mfma_f32_16x16x32_bf16((a),(b),(c),0,0,0)

__device__ __forceinline__ unsigned int cvt_pk(float a, float b) {
    union { __hip_bfloat162 h; unsigned int u; } c;
    c.h = __float22bfloat162_rn(make_float2(a, b));   // v_cvt_pk_bf16_f32
    return c.u;
}
__device__ __forceinline__ unsigned short f2bf(float f) {
    union { __hip_bfloat16 h; unsigned short u; } c;
    c.h = __float2bfloat16(f);
    return c.u;
}

// ws layout (bf16 elems): WqT [128][256] @0, WkT [128][256] @32768, WvT [128][128] @65536
__global__ void transpose_weights(const float* __restrict__ Wq,
                                  const float* __restrict__ Wk,
                                  const float* __restrict__ Wv,
                                  unsigned short* __restrict__ ws) {
    int t = blockIdx.x * 256 + threadIdx.x;
    if (t < 32768) {                // Wq (256x128) -> WqT
        int k = t >> 7, c = t & 127;
        ws[c * 256 + k] = f2bf(Wq[t]);
    } else if (t < 65536) {         // Wk
        int u = t - 32768; int k = u >> 7, c = u & 127;
        ws[32768 + c * 256 + k] = f2bf(Wk[u]);
    } else if (t < 81920) {         // Wv (128x128) -> WvT
        int u = t - 65536; int k = u >> 7, c = u & 127;
        ws[65536 + c * 128 + k] = f2bf(Wv[u]);
    }
}

// Pack two C-layout f32x4 tiles into bf16 pairs: lo16 = tile0, hi16 = tile1.
__device__ __forceinline__ u32x4 pack_pair(f32x4 t0, f32x4 t1) {
    u32x4 p;
    p.x = cvt_pk(t0[0], t1[0]);
    p.y = cvt_pk(t0[1], t1[1]);
    p.z = cvt_pk(t0[2], t1[2]);
    p.w = cvt_pk(t0[3], t1[3]);
    return p;
}

// In-register transpose: build a 16x16x32 A/B-fragment whose k-axis runs over the
// 32 s-rows held in two C-layout tiles packed as (lo=tile0, hi=tile1) in pk.
// C-layout: lane (q,d) reg r holds T[s_local=q*4+r][d].
// A-layout: lane (q',d) slot j holds T[s_local=q'*8+j][d]
//   -> tile = q'>>1, src quad = (q'&1)*2 + (j>>2), reg = j&3.
// One shfl pair moves both tiles; consumer selects half by (quad&2).
// Register-safe: by-value ext-vectors, swizzle access — no addressable locals.
__device__ __forceinline__ bf16x8 xpose_pk(u32x4 pk, int quad, int mr) {
    const int sb0 = ((quad & 1) * 2) * 16 + mr;   // src lane for j<4; +16 for j>=4
    u32x4 g0, g1;
    g0.x = __shfl(pk.x, sb0);      g0.y = __shfl(pk.y, sb0);
    g0.z = __shfl(pk.z, sb0);      g0.w = __shfl(pk.w, sb0);
    g1.x = __shfl(pk.x, sb0 + 16); g1.y = __shfl(pk.y, sb0 + 16);
    g1.z = __shfl(pk.z, sb0 + 16); g1.w = __shfl(pk.w, sb0 + 16);
    const unsigned int sh = (quad & 2) ? 16u : 0u;   // quads 2,3 take tile1 (hi half)
    u32x4 o;
    o.x = ((g0.x >> sh) & 0xffffu) | (((g0.y >> sh) & 0xffffu) << 16);
    o.y = ((g0.z >> sh) & 0xffffu) | (((g0.w >> sh) & 0xffffu) << 16);
    o.z = ((g1.x >> sh) & 0xffffu) | (((g1.y >> sh) & 0xffffu) << 16);
    o.w = ((g1.z >> sh) & 0xffffu) | (((g1.w >> sh) & 0xffffu) << 16);
    return __builtin_bit_cast(bf16x8, o);   // ext-vector <-> ext-vector: trivially copyable
}

// 512 threads = 8 waves; wave h owns head h end-to-end. Only cross-wave coupling:
// the cooperatively staged A-operands (x/guid, then query). 4 barriers total.
// LDS = 43,520 B. waves_per_eu(4): min 4 waves/SIMD -> 128-VGPR budget, no spill.
__global__ __launch_bounds__(512)
__attribute__((amdgpu_waves_per_eu(4)))
void attn_kernel(const float* __restrict__ query,   // (4,80,24,24,256) f32
                 const float* __restrict__ x,       // (2304,77,128) f32
                 const float* __restrict__ guid,    // (2304,77,128) f32
                 const unsigned short* __restrict__ wT,
                 const float* __restrict__ bq,
                 const float* __restrict__ bk,
                 const float* __restrict__ bv,
                 float* __restrict__ out)            // (2304,128) f32
{
    const int n    = blockIdx.x;
    const int tid  = threadIdx.x;
    const int h    = tid >> 6;      // wave = head 0..7
    const int lane = tid & 63;
    const int quad = lane >> 4;
    const int mr   = lane & 15;
    const int b    = n / 576;
    const int hw   = n % 576;

    __shared__ unsigned short stage[2][80 * CS];    // 2 x 21,760 B

    const unsigned short* WqT = wT;
    const unsigned short* WkT = wT + 32768;
    const unsigned short* WvT = wT + 65536;
    const f32x4 cZ = {0.f, 0.f, 0.f, 0.f};

    const float* xg = x    + (size_t)n * S77 * 128;
    const float* gg = guid + (size_t)n * S77 * 128;
    const int srow = tid >> 5;   // staging row within 16-row strip
    const int seg  = tid & 31;   // float4 segment within 128 cols

    const int cc = h * 16 + mr;                       // this lane's output channel
    const float bk_c = bk[cc], bv_c = bv[cc], bq_c = bq[cc];

    // Preload chunk-0 weights (no deps; L2 latency hides under staging)
    bf16x8 wk0[4], wv0[4];
    #pragma unroll
    for (int kk = 0; kk < 4; ++kk) {
        wk0[kk] = *(const bf16x8*)(WkT + cc * 256 + kk * 32 + quad * 8);
        wv0[kk] = *(const bf16x8*)(WvT + cc * 128 + kk * 32 + quad * 8);
    }

    float4 sb[5];
    // stage x -> buf0
    #pragma unroll
    for (int it = 0; it < 5; ++it) {
        const int s = srow + it * 16;
        if (s < S77) sb[it] = *(const float4*)(xg + (size_t)s * 128 + seg * 4);
    }
    #pragma unroll
    for (int it = 0; it < 5; ++it) {
        const int s = srow + it * 16;
        if (s < S77) {
            uint2 p; p.x = cvt_pk(sb[it].x, sb[it].y); p.y = cvt_pk(sb[it].z, sb[it].w);
            *(uint2*)&stage[0][s * CS + seg * 4] = p;
        }
    }
    // issue guid loads now; land during chunk-0 compute
    #pragma unroll
    for (int it = 0; it < 5; ++it) {
        const int s = srow + it * 16;
        if (s < S77) sb[it] = *(const float4*)(gg + (size_t)s * 128 + seg * 4);
    }
    __syncthreads();   // B1: buf0 (x) ready

    // ---- chunk 0: K += x@Wk[0:128], V = x@Wv (A-frags shared) ----
    f32x4 Kacc[5], Vacc[5];
    #pragma unroll
    for (int m = 0; m < 5; ++m) { Kacc[m] = cZ; Vacc[m] = cZ; }
    #pragma unroll
    for (int kk = 0; kk < 4; ++kk)
        #pragma unroll
        for (int m = 0; m < 5; ++m) {
            bf16x8 a = *(const bf16x8*)&stage[0][(m * 16 + mr) * CS + kk * 32 + quad * 8];
            Kacc[m] = MFMA(a, wk0[kk], Kacc[m]);
            Vacc[m] = MFMA(a, wv0[kk], Vacc[m]);
        }

    bf16x8 wk1[4];
    #pragma unroll
    for (int kk = 0; kk < 4; ++kk)
        wk1[kk] = *(const bf16x8*)(WkT + cc * 256 + 128 + kk * 32 + quad * 8);

    // write guid -> buf1; issue query chunk-0 loads
    #pragma unroll
    for (int it = 0; it < 5; ++it) {
        const int s = srow + it * 16;
        if (s < S77) {
            uint2 p; p.x = cvt_pk(sb[it].x, sb[it].y); p.y = cvt_pk(sb[it].z, sb[it].w);
            *(uint2*)&stage[1][s * CS + seg * 4] = p;
        }
    }
    #pragma unroll
    for (int it = 0; it < 5; ++it) {
        const int l = srow + it * 16;   // 0..79
        sb[it] = *(const float4*)(query + ((size_t)(b * 80 + l) * 576 + hw) * 256 + seg * 4);
    }
    __syncthreads();   // B2: buf1 (guid) ready; buf0 readers done

    // ---- chunk 1: K += guid@Wk[128:256] ----
    #pragma unroll
    for (int kk = 0; kk < 4; ++kk)
        #pragma unroll
        for (int m = 0; m < 5; ++m) {
            bf16x8 a = *(const bf16x8*)&stage[1][(m * 16 + mr) * CS + kk * 32 + quad * 8];
            Kacc[m] = MFMA(a, wk1[kk], Kacc[m]);
        }

    // ---- epilogue 1 (per-wave, no barrier): elu+1, mask, Ksum — IN PLACE ----
    float ksum = 0.f;
    #pragma unroll
    for (int m = 0; m < 5; ++m)
        #pragma unroll
        for (int r = 0; r < 4; ++r) {
            const int s = m * 16 + quad * 4 + r;
            float tk = 0.f, tv = 0.f;
            if (s < S77) {
                tk = Kacc[m][r] + bk_c;
                tk = (tk > 0.f) ? (tk + 1.f) : __expf(tk);   // elu+1
                tv = Vacc[m][r] + bv_c;
            }
            Kacc[m][r] = tk; Vacc[m][r] = tv; ksum += tk;
        }
    ksum += __shfl_xor(ksum, 16);   // sum over quads -> Ksum[d=mr] at every lane
    ksum += __shfl_xor(ksum, 32);

    // ---- in-register KV = Kf^T @ Vs (K=96, zero-padded via masked tiles) ----
    f32x4 KVacc = cZ;   // KV[d = quad*4+r][e = mr], 4 VGPRs, live to the end
    {
        bf16x8 af, bf;
        af = xpose_pk(pack_pair(Kacc[0], Kacc[1]), quad, mr);
        bf = xpose_pk(pack_pair(Vacc[0], Vacc[1]), quad, mr);
        KVacc = MFMA(af, bf, KVacc);
        af = xpose_pk(pack_pair(Kacc[2], Kacc[3]), quad, mr);
        bf = xpose_pk(pack_pair(Vacc[2], Vacc[3]), quad, mr);
        KVacc = MFMA(af, bf, KVacc);
        af = xpose_pk(pack_pair(Kacc[4], cZ), quad, mr);   // s 80..95 = zero tile
        bf = xpose_pk(pack_pair(Vacc[4], cZ), quad, mr);
        KVacc = MFMA(af, bf, KVacc);
    }

    // write query c0 -> buf0 (safe: buf0 readers done at B2); issue query c1 loads
    #pragma unroll
    for (int it = 0; it < 5; ++it) {
        const int l = srow + it * 16;
        uint2 p; p.x = cvt_pk(sb[it].x, sb[it].y); p.y = cvt_pk(sb[it].z, sb[it].w);
        *(uint2*)&stage[0][l * CS + seg * 4] = p;
    }
    #pragma unroll
    for (int it = 0; it < 5; ++it) {
        const int l = srow + it * 16;
        sb[it] = *(const float4*)(query + ((size_t)(b * 80 + l) * 576 + hw) * 256 + 128 + seg * 4);
    }
    bf16x8 wq0[4];
    #pragma unroll
    for (int kk = 0; kk < 4; ++kk)
        wq0[kk] = *(const bf16x8*)(WqT + cc * 256 + kk * 32 + quad * 8);
    __syncthreads();   // B3: buf0 (query c0) ready; buf1 readers done

    // ---- Q chunk 0 ----
    f32x4 Qacc[5];
    #pragma unroll
    for (int m = 0; m < 5; ++m) Qacc[m] = cZ;
    #pragma unroll
    for (int kk = 0; kk < 4; ++kk)
        #pragma unroll
        for (int m = 0; m < 5; ++m) {
            bf16x8 a = *(const bf16x8*)&stage[0][(m * 16 + mr) * CS + kk * 32 + quad * 8];
            Qacc[m] = MFMA(a, wq0[kk], Qacc[m]);
        }
    bf16x8 wq1[4];
    #pragma unroll
    for (int kk = 0; kk < 4; ++kk)
        wq1[kk] = *(const bf16x8*)(WqT + cc * 256 + 128 + kk * 32 + quad * 8);
    #pragma unroll
    for (int it = 0; it < 5; ++it) {
        const int l = srow + it * 16;
        uint2 p; p.x = cvt_pk(sb[it].x, sb[it].y); p.y = cvt_pk(sb[it].z, sb[it].w);
        *(uint2*)&stage[1][l * CS + seg * 4] = p;
    }
    __syncthreads();   // B4: buf1 (query c1) ready

    // ---- Q chunk 1 ----
    #pragma unroll
    for (int kk = 0; kk < 4; ++kk)
        #pragma unroll
        for (int m = 0; m < 5; ++m) {
            bf16x8 a = *(const bf16x8*)&stage[1][(m * 16 + mr) * CS + kk * 32 + quad * 8];
            Qacc[m] = MFMA(a, wq1[kk], Qacc[m]);
        }

    // ---- epilogue 2 (per-wave): z, qbar, out — all in-register ----
    float qbar = 0.f;
    #pragma unroll
    for (int m = 0; m < 5; ++m)
        #pragma unroll
        for (int r = 0; r < 4; ++r) {
            float qv = Qacc[m][r] + bq_c;
            qv = (qv > 0.f) ? (qv + 1.f) : __expf(qv);   // elu+1 (l always < 80)
            float den = qv * ksum;
            den += __shfl_xor(den, 1);   // dot over d = mr lanes (same l across quad)
            den += __shfl_xor(den, 2);
            den += __shfl_xor(den, 4);
            den += __shfl_xor(den, 8);
            qbar += qv * (1.f / (den + 1e-6f));          // z_l * Q[l,d]
        }
    qbar += __shfl_xor(qbar, 16);   // sum over quads -> Qbar[d=mr] at every lane
    qbar += __shfl_xor(qbar, 32);

    float o = 0.f;
    #pragma unroll
    for (int r = 0; r < 4; ++r) {
        const float qb_r = __shfl(qbar, quad * 4 + r);   // Qbar[quad*4+r]
        o += qb_r * KVacc[r];                            // KV[quad*4+r][mr]
    }
    o += __shfl_xor(o, 16);   // sum over quads -> full d contraction
    o += __shfl_xor(o, 32);
    if (quad == 0) out[(size_t)n * 128 + cc] = o * (1.f / 80.f);
}

extern "C" void kernel_launch(void* const* d_in, const int* in_sizes, int n_in,
                              void* d_out, int out_size, void* d_ws, size_t ws_size,
                              hipStream_t stream) {
    const float* query = (const float*)d_in[0];
    const float* x     = (const float*)d_in[1];
    const float* g     = (const float*)d_in[2];
    const float* Wq    = (const float*)d_in[3];
    const float* bq    = (const float*)d_in[4];
    const float* Wk    = (const float*)d_in[5];
    const float* bk    = (const float*)d_in[6];
    const float* Wv    = (const float*)d_in[7];
    const float* bv    = (const float*)d_in[8];
    float* out = (float*)d_out;
    unsigned short* ws = (unsigned short*)d_ws;   // 163,840 B used

    hipLaunchKernelGGL(transpose_weights, dim3(320), dim3(256), 0, stream, Wq, Wk, Wv, ws);
    hipLaunchKernelGGL(attn_kernel, dim3(2304), dim3(512), 0, stream,
                       query, x, g, ws, bq, bk, bv, out);
}